// Round 1
// baseline (610.898 us; speedup 1.0000x reference)
//
#include <hip/hip_runtime.h>
#include <math.h>

#define IN_CH   256
#define HIDDEN  8
#define NBASIS  8
#define OUT_CH  2
#define HWD     25600      // H*W = 160*160
#define BATCH   16
#define PPT     4          // pixels per thread (float4)

// One thread handles 4 consecutive pixels. Loop over the 256 input channels
// (stride HWD between channels), accumulate the 8 hidden projections in
// registers; conv_w staged transposed in LDS ([c][k], uniform broadcast
// reads). Epilogue: 8x8 RBF basis + 2-channel linear head, float4 stores.
__global__ __launch_bounds__(256) void rbf_fused_kernel(
    const float* __restrict__ x,
    const float* __restrict__ conv_w,      // [HIDDEN][IN_CH]
    const float* __restrict__ conv_b,      // [HIDDEN]
    const float* __restrict__ centers,     // [HIDDEN][NBASIS] (flat)
    const float* __restrict__ log_widths,  // [HIDDEN][NBASIS] (flat)
    const float* __restrict__ out_w,       // [OUT_CH][HIDDEN][NBASIS]
    const float* __restrict__ out_bias,    // [OUT_CH]
    float* __restrict__ out)               // [BATCH][OUT_CH][HWD]
{
    __shared__ float s_w[IN_CH][HIDDEN];        // 8 KiB, transposed conv_w
    __shared__ float s_cen[HIDDEN * NBASIS];
    __shared__ float s_iw[HIDDEN * NBASIS];     // 1/width
    __shared__ float s_ow0[HIDDEN * NBASIS];
    __shared__ float s_ow1[HIDDEN * NBASIS];
    __shared__ float s_cb[HIDDEN];
    __shared__ float s_ob[OUT_CH];

    const int tid = threadIdx.x;

    // Stage weights. Store pattern: i -> s_w[i>>3][i&7] = flat offset i -> conflict-free.
    for (int i = tid; i < IN_CH * HIDDEN; i += 256) {
        const int c = i >> 3, k = i & 7;
        s_w[c][k] = conv_w[k * IN_CH + c];
    }
    if (tid < HIDDEN * NBASIS) {
        s_cen[tid] = centers[tid];
        const float wdt = log1pf(__expf(log_widths[tid])) + 0.001f;  // softplus + eps
        s_iw[tid]  = 1.0f / wdt;
        s_ow0[tid] = out_w[tid];
        s_ow1[tid] = out_w[HIDDEN * NBASIS + tid];
    }
    if (tid < HIDDEN) s_cb[tid] = conv_b[tid];
    if (tid < OUT_CH) s_ob[tid] = out_bias[tid];
    __syncthreads();

    const long long g  = (long long)blockIdx.x * 256 + tid;  // pixel-group id
    const long long p0 = g * PPT;                            // first pixel
    const int b  = (int)(p0 / HWD);                          // HWD % 4 == 0: no straddle
    const int hw = (int)(p0 % HWD);
    const float* xp = x + (long long)b * IN_CH * HWD + hw;

    float acc[HIDDEN][PPT];
    #pragma unroll
    for (int k = 0; k < HIDDEN; ++k) {
        const float cb = s_cb[k];
        acc[k][0] = cb; acc[k][1] = cb; acc[k][2] = cb; acc[k][3] = cb;
    }

    // Main streaming loop: 1 float4 global load + 8 broadcast LDS reads + 32 FMA per iter.
    #pragma unroll 8
    for (int c = 0; c < IN_CH; ++c) {
        const float4 xv = *reinterpret_cast<const float4*>(xp + (long long)c * HWD);
        #pragma unroll
        for (int k = 0; k < HIDDEN; ++k) {
            const float w = s_w[c][k];
            acc[k][0] = fmaf(xv.x, w, acc[k][0]);
            acc[k][1] = fmaf(xv.y, w, acc[k][1]);
            acc[k][2] = fmaf(xv.z, w, acc[k][2]);
            acc[k][3] = fmaf(xv.w, w, acc[k][3]);
        }
    }

    // Epilogue: phi = exp(-((z-c)*iw)^2); out[o] = sum phi * w[o] + bias.
    float o0[PPT], o1[PPT];
    #pragma unroll
    for (int p = 0; p < PPT; ++p) { o0[p] = s_ob[0]; o1[p] = s_ob[1]; }

    #pragma unroll
    for (int k = 0; k < HIDDEN; ++k) {
        #pragma unroll
        for (int j = 0; j < NBASIS; ++j) {
            const int   kj  = k * NBASIS + j;
            const float cen = s_cen[kj];
            const float iw  = s_iw[kj];
            const float w0  = s_ow0[kj];
            const float w1  = s_ow1[kj];
            #pragma unroll
            for (int p = 0; p < PPT; ++p) {
                const float t   = (acc[k][p] - cen) * iw;
                const float phi = __expf(-t * t);
                o0[p] = fmaf(phi, w0, o0[p]);
                o1[p] = fmaf(phi, w1, o1[p]);
            }
        }
    }

    float* op0 = out + ((long long)b * OUT_CH + 0) * HWD + hw;
    float* op1 = out + ((long long)b * OUT_CH + 1) * HWD + hw;
    *reinterpret_cast<float4*>(op0) = make_float4(o0[0], o0[1], o0[2], o0[3]);
    *reinterpret_cast<float4*>(op1) = make_float4(o1[0], o1[1], o1[2], o1[3]);
}

extern "C" void kernel_launch(void* const* d_in, const int* in_sizes, int n_in,
                              void* d_out, int out_size, void* d_ws, size_t ws_size,
                              hipStream_t stream) {
    const float* x          = (const float*)d_in[0];
    const float* conv_w     = (const float*)d_in[1];
    const float* conv_b     = (const float*)d_in[2];
    const float* centers    = (const float*)d_in[3];
    const float* log_widths = (const float*)d_in[4];
    const float* out_w      = (const float*)d_in[5];
    const float* out_bias   = (const float*)d_in[6];
    float* out = (float*)d_out;

    const int groups = BATCH * HWD / PPT;    // 102400
    const int blocks = groups / 256;         // 400
    rbf_fused_kernel<<<blocks, 256, 0, stream>>>(
        x, conv_w, conv_b, centers, log_widths, out_w, out_bias, out);
}

// Round 2
// 563.927 us; speedup vs baseline: 1.0833x; 1.0833x over previous
//
#include <hip/hip_runtime.h>
#include <math.h>

#define IN_CH   256
#define HIDDEN  8
#define NBASIS  8
#define OUT_CH  2
#define HWD     25600      // H*W = 160*160
#define BATCH   16
#define PPT     2          // pixels per thread (float2)
#define PF      8          // prefetch pipeline depth

// One thread handles 2 consecutive pixels. Explicit 8-deep register prefetch
// pipeline over the 256 input channels (stride HWD) keeps 8 global loads in
// flight per wave (4 KB/wave). 800 blocks -> 12.5 waves/CU of TLP on top.
// conv_w transposed in LDS ([c][k], read as 2x ds_read_b128 broadcast).
// Epilogue: 8x8 RBF basis + 2-channel linear head in registers.
__global__ __launch_bounds__(256) void rbf_fused_kernel(
    const float* __restrict__ x,
    const float* __restrict__ conv_w,      // [HIDDEN][IN_CH]
    const float* __restrict__ conv_b,      // [HIDDEN]
    const float* __restrict__ centers,     // [HIDDEN][NBASIS] (flat)
    const float* __restrict__ log_widths,  // [HIDDEN][NBASIS] (flat)
    const float* __restrict__ out_w,       // [OUT_CH][HIDDEN][NBASIS]
    const float* __restrict__ out_bias,    // [OUT_CH]
    float* __restrict__ out)               // [BATCH][OUT_CH][HWD]
{
    __shared__ float s_w[IN_CH][HIDDEN];        // 8 KiB, transposed conv_w
    __shared__ float s_cen[HIDDEN * NBASIS];
    __shared__ float s_iw[HIDDEN * NBASIS];     // 1/width
    __shared__ float s_ow0[HIDDEN * NBASIS];
    __shared__ float s_ow1[HIDDEN * NBASIS];
    __shared__ float s_cb[HIDDEN];
    __shared__ float s_ob[OUT_CH];

    const int tid = threadIdx.x;

    for (int i = tid; i < IN_CH * HIDDEN; i += 256) {
        const int c = i >> 3, k = i & 7;
        s_w[c][k] = conv_w[k * IN_CH + c];      // store flat offset i: conflict-free
    }
    if (tid < HIDDEN * NBASIS) {
        s_cen[tid] = centers[tid];
        const float wdt = log1pf(__expf(log_widths[tid])) + 0.001f;  // softplus + eps
        s_iw[tid]  = 1.0f / wdt;
        s_ow0[tid] = out_w[tid];
        s_ow1[tid] = out_w[HIDDEN * NBASIS + tid];
    }
    if (tid < HIDDEN) s_cb[tid] = conv_b[tid];
    if (tid < OUT_CH) s_ob[tid] = out_bias[tid];
    __syncthreads();

    const int g  = blockIdx.x * 256 + tid;      // pixel-pair id
    const int p0 = g * PPT;                     // first pixel (fits int: <= 409600)
    const int b  = p0 / HWD;                    // HWD % 2 == 0: no straddle
    const int hw = p0 % HWD;
    const float* xp = x + b * (IN_CH * HWD) + hw;   // max offset ~105M elems: int-safe

    float acc[HIDDEN][PPT];
    #pragma unroll
    for (int k = 0; k < HIDDEN; ++k) {
        const float cb = s_cb[k];
        acc[k][0] = cb; acc[k][1] = cb;
    }

    // ---- 8-deep prefetch pipeline over channels ----
    float2 buf[PF];
    #pragma unroll
    for (int j = 0; j < PF; ++j)
        buf[j] = *reinterpret_cast<const float2*>(xp + j * HWD);

    // steady state: 31 outer iterations, each consumes 8 channels and issues
    // the next 8 loads BEFORE the FMAs that consume the current values.
    for (int c0 = 0; c0 < IN_CH - PF; c0 += PF) {
        #pragma unroll
        for (int j = 0; j < PF; ++j) {
            const float2 xv = buf[j];
            buf[j] = *reinterpret_cast<const float2*>(xp + (c0 + PF + j) * HWD);
            const int c = c0 + j;
            const float4 wlo = *reinterpret_cast<const float4*>(&s_w[c][0]);
            const float4 whi = *reinterpret_cast<const float4*>(&s_w[c][4]);
            acc[0][0] = fmaf(xv.x, wlo.x, acc[0][0]); acc[0][1] = fmaf(xv.y, wlo.x, acc[0][1]);
            acc[1][0] = fmaf(xv.x, wlo.y, acc[1][0]); acc[1][1] = fmaf(xv.y, wlo.y, acc[1][1]);
            acc[2][0] = fmaf(xv.x, wlo.z, acc[2][0]); acc[2][1] = fmaf(xv.y, wlo.z, acc[2][1]);
            acc[3][0] = fmaf(xv.x, wlo.w, acc[3][0]); acc[3][1] = fmaf(xv.y, wlo.w, acc[3][1]);
            acc[4][0] = fmaf(xv.x, whi.x, acc[4][0]); acc[4][1] = fmaf(xv.y, whi.x, acc[4][1]);
            acc[5][0] = fmaf(xv.x, whi.y, acc[5][0]); acc[5][1] = fmaf(xv.y, whi.y, acc[5][1]);
            acc[6][0] = fmaf(xv.x, whi.z, acc[6][0]); acc[6][1] = fmaf(xv.y, whi.z, acc[6][1]);
            acc[7][0] = fmaf(xv.x, whi.w, acc[7][0]); acc[7][1] = fmaf(xv.y, whi.w, acc[7][1]);
        }
    }
    // drain: last 8 channels, no prefetch.
    {
        const int c0 = IN_CH - PF;
        #pragma unroll
        for (int j = 0; j < PF; ++j) {
            const float2 xv = buf[j];
            const int c = c0 + j;
            const float4 wlo = *reinterpret_cast<const float4*>(&s_w[c][0]);
            const float4 whi = *reinterpret_cast<const float4*>(&s_w[c][4]);
            acc[0][0] = fmaf(xv.x, wlo.x, acc[0][0]); acc[0][1] = fmaf(xv.y, wlo.x, acc[0][1]);
            acc[1][0] = fmaf(xv.x, wlo.y, acc[1][0]); acc[1][1] = fmaf(xv.y, wlo.y, acc[1][1]);
            acc[2][0] = fmaf(xv.x, wlo.z, acc[2][0]); acc[2][1] = fmaf(xv.y, wlo.z, acc[2][1]);
            acc[3][0] = fmaf(xv.x, wlo.w, acc[3][0]); acc[3][1] = fmaf(xv.y, wlo.w, acc[3][1]);
            acc[4][0] = fmaf(xv.x, whi.x, acc[4][0]); acc[4][1] = fmaf(xv.y, whi.x, acc[4][1]);
            acc[5][0] = fmaf(xv.x, whi.y, acc[5][0]); acc[5][1] = fmaf(xv.y, whi.y, acc[5][1]);
            acc[6][0] = fmaf(xv.x, whi.z, acc[6][0]); acc[6][1] = fmaf(xv.y, whi.z, acc[6][1]);
            acc[7][0] = fmaf(xv.x, whi.w, acc[7][0]); acc[7][1] = fmaf(xv.y, whi.w, acc[7][1]);
        }
    }

    // Epilogue: phi = exp(-((z-c)*iw)^2); out[o] = sum phi * w[o] + bias.
    float o0[PPT], o1[PPT];
    #pragma unroll
    for (int p = 0; p < PPT; ++p) { o0[p] = s_ob[0]; o1[p] = s_ob[1]; }

    #pragma unroll
    for (int k = 0; k < HIDDEN; ++k) {
        #pragma unroll
        for (int j = 0; j < NBASIS; ++j) {
            const int   kj  = k * NBASIS + j;
            const float cen = s_cen[kj];
            const float iw  = s_iw[kj];
            const float w0  = s_ow0[kj];
            const float w1  = s_ow1[kj];
            #pragma unroll
            for (int p = 0; p < PPT; ++p) {
                const float t   = (acc[k][p] - cen) * iw;
                const float phi = __expf(-t * t);
                o0[p] = fmaf(phi, w0, o0[p]);
                o1[p] = fmaf(phi, w1, o1[p]);
            }
        }
    }

    float* op0 = out + (b * OUT_CH + 0) * HWD + hw;
    float* op1 = out + (b * OUT_CH + 1) * HWD + hw;
    *reinterpret_cast<float2*>(op0) = make_float2(o0[0], o0[1]);
    *reinterpret_cast<float2*>(op1) = make_float2(o1[0], o1[1]);
}

extern "C" void kernel_launch(void* const* d_in, const int* in_sizes, int n_in,
                              void* d_out, int out_size, void* d_ws, size_t ws_size,
                              hipStream_t stream) {
    const float* x          = (const float*)d_in[0];
    const float* conv_w     = (const float*)d_in[1];
    const float* conv_b     = (const float*)d_in[2];
    const float* centers    = (const float*)d_in[3];
    const float* log_widths = (const float*)d_in[4];
    const float* out_w      = (const float*)d_in[5];
    const float* out_bias   = (const float*)d_in[6];
    float* out = (float*)d_out;

    const int groups = BATCH * HWD / PPT;    // 204800
    const int blocks = groups / 256;         // 800
    rbf_fused_kernel<<<blocks, 256, 0, stream>>>(
        x, conv_w, conv_b, centers, log_widths, out_w, out_bias, out);
}